// Round 8
// baseline (243.937 us; speedup 1.0000x reference)
//
#include <hip/hip_runtime.h>
#include <hip/hip_bf16.h>
#include <hip/hip_cooperative_groups.h>

namespace cg = cooperative_groups;

// SimpleGraphConv (RGCN-mean), fused aggregate-first, pair-interleaved register-gather:
//   out[n] = bias + sum_r ( mean_{e: dst=n, type=r} x[src[e]] ) @ W[r]
//
//   memset -> pre(hist+wconv+xconv) -> coop_scan(1+2+3, grid.sync) -> place -> fused
//
//   fused: per 64-row tile, relations processed in PAIRS:
//     gather both rels' A-fragments in lockstep (2 independent chains/lane,
//     trip = max(n0,n1)), then {stage W_p0; bar; MFMA p0; bar; stage W_p1;
//     bar; MFMA p1; bar}. acc held across all rels; out written once.

#define C128 128
#define BR 64

typedef __attribute__((ext_vector_type(8))) short short8;
typedef __attribute__((ext_vector_type(4))) float f32x4;

__device__ __forceinline__ void gload_lds16(void* lds, const void* gsrc) {
    __builtin_amdgcn_global_load_lds(
        (const __attribute__((address_space(1))) unsigned int*)gsrc,
        (__attribute__((address_space(3))) unsigned int*)lds, 16, 0, 0);
}

__device__ __forceinline__ float bf16u_f32(unsigned short u) {
    union { unsigned int i; float f; } c;
    c.i = ((unsigned int)u) << 16;
    return c.f;
}

// ------- merged: hist | wconv | xconv (independent work, block-split) -------

__global__ __launch_bounds__(256) void pre_kernel(const int* __restrict__ ei,
                                                  const int* __restrict__ et,
                                                  unsigned* __restrict__ cursor,
                                                  const float* __restrict__ W,
                                                  __hip_bfloat16* __restrict__ WbT,
                                                  const float* __restrict__ x,
                                                  __hip_bfloat16* __restrict__ xb,
                                                  int n_edges, int n_nodes,
                                                  int hblk, int wblk, int wtot, int xt8) {
    int bid = blockIdx.x;
    if (bid < hblk) {
        int e = bid * 256 + threadIdx.x;
        if (e < n_edges)
            atomicAdd(&cursor[(size_t)et[e] * n_nodes + ei[n_edges + e]], 1u);
    } else if (bid < hblk + wblk) {
        int i = (bid - hblk) * 256 + threadIdx.x;
        if (i < wtot) {
            int r = i >> 14, k = (i >> 7) & 127, n = i & 127;
            WbT[(r << 14) + (n << 7) + ((((k >> 3) ^ (n & 7)) << 3) | (k & 7))] =
                __float2bfloat16(W[i]);
        }
    } else {
        int i = (bid - hblk - wblk) * 256 + threadIdx.x;
        if (i < xt8) {
            const float4* src = reinterpret_cast<const float4*>(x + (size_t)i * 8);
            float4 v0 = src[0], v1 = src[1];
            short8 o;
            o[0] = (short)__bfloat16_as_ushort(__float2bfloat16(v0.x));
            o[1] = (short)__bfloat16_as_ushort(__float2bfloat16(v0.y));
            o[2] = (short)__bfloat16_as_ushort(__float2bfloat16(v0.z));
            o[3] = (short)__bfloat16_as_ushort(__float2bfloat16(v0.w));
            o[4] = (short)__bfloat16_as_ushort(__float2bfloat16(v1.x));
            o[5] = (short)__bfloat16_as_ushort(__float2bfloat16(v1.y));
            o[6] = (short)__bfloat16_as_ushort(__float2bfloat16(v1.z));
            o[7] = (short)__bfloat16_as_ushort(__float2bfloat16(v1.w));
            *reinterpret_cast<short8*>(reinterpret_cast<unsigned short*>(xb) + (size_t)i * 8) = o;
        }
    }
}

// ------- cooperative scan: scan1 | scan2 | scan3 in one launch -------
// grid = nblk = ceil(RN/1024) blocks x 256 (391 for this problem: co-resident)

__global__ __launch_bounds__(256) void scan_kernel(unsigned* __restrict__ cursor,
                                                   unsigned* __restrict__ off,
                                                   unsigned* __restrict__ part,
                                                   int total, int n_edges) {
    cg::grid_group grid = cg::this_grid();
    __shared__ unsigned s[256];
    const int t = threadIdx.x;
    const int bid = blockIdx.x;
    const int base = bid * 1024 + t * 4;

    // P1: block partial sums
    {
        unsigned sum = 0;
#pragma unroll
        for (int i = 0; i < 4; ++i) {
            int idx = base + i;
            if (idx < total) sum += cursor[idx];
        }
        s[t] = sum;
        __syncthreads();
        for (int d = 128; d > 0; d >>= 1) {
            if (t < d) s[t] += s[t + d];
            __syncthreads();
        }
        if (t == 0) part[bid] = s[0];
    }
    grid.sync();

    // P2: block 0 exclusive-scans part[]
    if (bid == 0) {
        int nb = gridDim.x;
        unsigned run = 0;
        for (int b2 = 0; b2 < nb; b2 += 256) {
            int i = b2 + t;
            unsigned v = (i < nb) ? part[i] : 0u;
            s[t] = v;
            __syncthreads();
            for (int d = 1; d < 256; d <<= 1) {
                unsigned u = (t >= d) ? s[t - d] : 0u;
                __syncthreads();
                s[t] += u;
                __syncthreads();
            }
            if (i < nb) part[i] = run + s[t] - v;
            unsigned tot = s[255];
            __syncthreads();
            run += tot;
        }
    }
    grid.sync();

    // P3: per-block exclusive scan -> off, cursor (place cursors)
    {
        unsigned v[4];
        unsigned tsum = 0;
#pragma unroll
        for (int i = 0; i < 4; ++i) {
            int idx = base + i;
            v[i] = (idx < total) ? cursor[idx] : 0u;
            tsum += v[i];
        }
        s[t] = tsum;
        __syncthreads();
        for (int d = 1; d < 256; d <<= 1) {
            unsigned u = (t >= d) ? s[t - d] : 0u;
            __syncthreads();
            s[t] += u;
            __syncthreads();
        }
        unsigned run = s[t] - tsum + part[bid];
#pragma unroll
        for (int i = 0; i < 4; ++i) {
            int idx = base + i;
            if (idx < total) {
                off[idx] = run;
                cursor[idx] = run;
                run += v[i];
            }
        }
        if (bid == 0 && t == 0) off[total] = (unsigned)n_edges;
    }
}

__global__ __launch_bounds__(256) void place_kernel(const int* __restrict__ ei,
                                                    const int* __restrict__ et,
                                                    unsigned* __restrict__ cursor,
                                                    int* __restrict__ sorted_src,
                                                    int n_edges, int n_nodes) {
    int e = blockIdx.x * 256 + threadIdx.x;
    if (e < n_edges) {
        int src = ei[e];
        int dst = ei[n_edges + e];
        int key = et[e] * n_nodes + dst;
        unsigned pos = atomicAdd(&cursor[key], 1u);
        sorted_src[pos] = src;
    }
}

// ---------------- fused pair-interleaved register-gather + MFMA GEMM ----------------

__global__ __launch_bounds__(256, 3) void fused_kernel(
    const __hip_bfloat16* __restrict__ xb, const int* __restrict__ ss,
    const unsigned* __restrict__ off, const __hip_bfloat16* __restrict__ WbT,
    const float* __restrict__ bias, float* __restrict__ out,
    int n_nodes, int n_rel) {
    __shared__ __align__(16) __hip_bfloat16 sW[C128 * C128];  // 32 KB, swizzled
    const int t = threadIdx.x, lane = t & 63, w = t >> 6;
    const int l16 = lane & 15, cg = lane >> 4;
    const int row0 = blockIdx.x * BR;
    const int rl = w * 16 + l16;   // tile row owned (4 cg-lanes per row)
    const int node = row0 + rl;
    const bool live = (node < n_nodes);
    const unsigned short* xbu = reinterpret_cast<const unsigned short*>(xb);

    f32x4 acc[8];
#pragma unroll
    for (int i = 0; i < 8; ++i) acc[i] = (f32x4){0.f, 0.f, 0.f, 0.f};

#define STAGE_W(P)                                                              \
    {                                                                           \
        const char* wp_ = (const char*)(WbT + ((size_t)(P) << 14));             \
        _Pragma("unroll") for (int i_ = 0; i_ < 8; ++i_) {                      \
            int seg_ = i_ * 4 + w;                                              \
            gload_lds16((char*)sW + seg_ * 1024 + lane * 16,                    \
                        wp_ + seg_ * 1024 + lane * 16);                         \
        }                                                                       \
    }

#define MFMA_REL(AF)                                                            \
    _Pragma("unroll") for (int kt_ = 0; kt_ < 4; ++kt_) {                       \
        int chunk_ = kt_ * 4 + cg;                                              \
        _Pragma("unroll") for (int nt_ = 0; nt_ < 8; ++nt_) {                   \
            int wn_ = nt_ * 16 + l16;                                           \
            short8 bf_ = *reinterpret_cast<const short8*>(                      \
                &sW[(wn_ << 7) + ((chunk_ ^ (wn_ & 7)) << 3)]);                 \
            acc[nt_] = __builtin_amdgcn_mfma_f32_16x16x32_bf16(AF[kt_], bf_,    \
                                                               acc[nt_], 0, 0, 0); \
        }                                                                       \
    }

    int p = 0;
    for (; p + 1 < n_rel; p += 2) {
        // CSR runs for both rels of the pair (independent loads, issued early)
        unsigned b0 = 0, e0 = 0, b1 = 0, e1 = 0;
        if (live) {
            size_t k0 = (size_t)p * n_nodes + node;
            size_t k1 = k0 + (size_t)n_nodes;
            b0 = off[k0]; e0 = off[k0 + 1];
            b1 = off[k1]; e1 = off[k1 + 1];
        }
        STAGE_W(p);  // async; overlaps the pair gather

        int n0 = (int)(e0 - b0), n1 = (int)(e1 - b1);
        int nm = n0 > n1 ? n0 : n1;
        float a0[4][8], a1[4][8];
#pragma unroll
        for (int kt = 0; kt < 4; ++kt)
#pragma unroll
            for (int j = 0; j < 8; ++j) { a0[kt][j] = 0.f; a1[kt][j] = 0.f; }

        int s0 = (n0 > 0) ? ss[b0] : 0;
        int s1 = (n1 > 0) ? ss[b1] : 0;
        for (int i = 0; i < nm; ++i) {
            if (i < n0) {
                const unsigned short* rp = xbu + ((size_t)s0 << 7) + cg * 8;
                short8 v0 = *reinterpret_cast<const short8*>(rp);
                short8 v1 = *reinterpret_cast<const short8*>(rp + 32);
                short8 v2 = *reinterpret_cast<const short8*>(rp + 64);
                short8 v3 = *reinterpret_cast<const short8*>(rp + 96);
                s0 = (i + 1 < n0) ? ss[(int)b0 + i + 1] : 0;
#pragma unroll
                for (int j = 0; j < 8; ++j) {
                    a0[0][j] += bf16u_f32((unsigned short)v0[j]);
                    a0[1][j] += bf16u_f32((unsigned short)v1[j]);
                    a0[2][j] += bf16u_f32((unsigned short)v2[j]);
                    a0[3][j] += bf16u_f32((unsigned short)v3[j]);
                }
            }
            if (i < n1) {
                const unsigned short* rp = xbu + ((size_t)s1 << 7) + cg * 8;
                short8 v0 = *reinterpret_cast<const short8*>(rp);
                short8 v1 = *reinterpret_cast<const short8*>(rp + 32);
                short8 v2 = *reinterpret_cast<const short8*>(rp + 64);
                short8 v3 = *reinterpret_cast<const short8*>(rp + 96);
                s1 = (i + 1 < n1) ? ss[(int)b1 + i + 1] : 0;
#pragma unroll
                for (int j = 0; j < 8; ++j) {
                    a1[0][j] += bf16u_f32((unsigned short)v0[j]);
                    a1[1][j] += bf16u_f32((unsigned short)v1[j]);
                    a1[2][j] += bf16u_f32((unsigned short)v2[j]);
                    a1[3][j] += bf16u_f32((unsigned short)v3[j]);
                }
            }
        }
        float i0 = (n0 > 0) ? 1.0f / (float)n0 : 0.0f;
        float i1 = (n1 > 0) ? 1.0f / (float)n1 : 0.0f;
        short8 af0[4], af1[4];
#pragma unroll
        for (int kt = 0; kt < 4; ++kt) {
            short8 o0, o1;
#pragma unroll
            for (int j = 0; j < 8; ++j) {
                o0[j] = (short)__bfloat16_as_ushort(__float2bfloat16(a0[kt][j] * i0));
                o1[j] = (short)__bfloat16_as_ushort(__float2bfloat16(a1[kt][j] * i1));
            }
            af0[kt] = o0;
            af1[kt] = o1;
        }

        __syncthreads();   // sW(p) ready (drains vmcnt)
        MFMA_REL(af0);
        __syncthreads();   // sW reads done
        STAGE_W(p + 1);
        __syncthreads();   // sW(p+1) ready
        MFMA_REL(af1);
        __syncthreads();   // sW reads done before next pair restages
    }
    // odd tail relation
    if (p < n_rel) {
        unsigned b0 = 0, e0 = 0;
        if (live) {
            size_t k0 = (size_t)p * n_nodes + node;
            b0 = off[k0]; e0 = off[k0 + 1];
        }
        STAGE_W(p);
        int n0 = (int)(e0 - b0);
        float a0[4][8];
#pragma unroll
        for (int kt = 0; kt < 4; ++kt)
#pragma unroll
            for (int j = 0; j < 8; ++j) a0[kt][j] = 0.f;
        int s0 = (n0 > 0) ? ss[b0] : 0;
        for (int i = 0; i < n0; ++i) {
            const unsigned short* rp = xbu + ((size_t)s0 << 7) + cg * 8;
            short8 v0 = *reinterpret_cast<const short8*>(rp);
            short8 v1 = *reinterpret_cast<const short8*>(rp + 32);
            short8 v2 = *reinterpret_cast<const short8*>(rp + 64);
            short8 v3 = *reinterpret_cast<const short8*>(rp + 96);
            s0 = (i + 1 < n0) ? ss[(int)b0 + i + 1] : 0;
#pragma unroll
            for (int j = 0; j < 8; ++j) {
                a0[0][j] += bf16u_f32((unsigned short)v0[j]);
                a0[1][j] += bf16u_f32((unsigned short)v1[j]);
                a0[2][j] += bf16u_f32((unsigned short)v2[j]);
                a0[3][j] += bf16u_f32((unsigned short)v3[j]);
            }
        }
        float i0 = (n0 > 0) ? 1.0f / (float)n0 : 0.0f;
        short8 af0[4];
#pragma unroll
        for (int kt = 0; kt < 4; ++kt) {
            short8 o0;
#pragma unroll
            for (int j = 0; j < 8; ++j)
                o0[j] = (short)__bfloat16_as_ushort(__float2bfloat16(a0[kt][j] * i0));
            af0[kt] = o0;
        }
        __syncthreads();
        MFMA_REL(af0);
        __syncthreads();
    }

    // epilogue: D row = 4*(lane>>4)+i, col = lane&15 (per 16x16 tile)
    const int rbase = row0 + w * 16 + (cg << 2);
#pragma unroll
    for (int nt = 0; nt < 8; ++nt) {
        int col = nt * 16 + l16;
        float b = bias[col];
#pragma unroll
        for (int i = 0; i < 4; ++i) {
            int r = rbase + i;
            if (r < n_nodes)
                out[(size_t)r * C128 + col] = acc[nt][i] + b;
        }
    }
#undef STAGE_W
#undef MFMA_REL
}

// ---------------- host ----------------

static inline char* align16p(char* p) {
    return (char*)(((uintptr_t)p + 15) & ~(uintptr_t)15);
}

extern "C" void kernel_launch(void* const* d_in, const int* in_sizes, int n_in,
                              void* d_out, int out_size, void* d_ws, size_t ws_size,
                              hipStream_t stream) {
    const float* x    = (const float*)d_in[0];
    const int*   ei   = (const int*)d_in[1];   // [2][E]
    const int*   et   = (const int*)d_in[2];   // [E]
    const float* W    = (const float*)d_in[3]; // [R][128][128]
    const float* bias = (const float*)d_in[4]; // [128]
    float* out = (float*)d_out;

    const int n_nodes = in_sizes[0] / C128;
    const int n_edges = in_sizes[2];
    const int n_rel   = in_sizes[3] / (C128 * C128);
    const int RN = n_rel * n_nodes;

    // workspace: off | cursor | part | sorted_src | WbT | xb   (~19 MB)
    char* p = (char*)d_ws;
    unsigned* off = (unsigned*)p;      p += (size_t)(RN + 1) * 4; p = align16p(p);
    unsigned* cursor = (unsigned*)p;   p += (size_t)RN * 4;       p = align16p(p);
    unsigned* part = (unsigned*)p;     p += 4096 * 4;
    int* sorted_src = (int*)p;         p += (size_t)n_edges * 4;  p = align16p(p);
    __hip_bfloat16* WbT = (__hip_bfloat16*)p; p += (size_t)n_rel * C128 * C128 * 2; p = align16p(p);
    __hip_bfloat16* xb = (__hip_bfloat16*)p;

    hipMemsetAsync(cursor, 0, (size_t)RN * 4, stream);

    // hist + wconv + xconv in one launch (right-sized grid, block-range split)
    int wtot = n_rel * C128 * C128;
    int xt8 = n_nodes * (C128 / 8);
    int hblk = (n_edges + 255) / 256;
    int wblk = (wtot + 255) / 256;
    int xblk = (xt8 + 255) / 256;
    pre_kernel<<<hblk + wblk + xblk, 256, 0, stream>>>(ei, et, cursor, W, WbT, x, xb,
                                                       n_edges, n_nodes, hblk, wblk, wtot, xt8);

    // cooperative scan (scan1+2+3 fused via grid.sync)
    int nblk = (RN + 1023) / 1024;
    {
        unsigned* cursor_a = cursor;
        unsigned* off_a = off;
        unsigned* part_a = part;
        int RN_a = RN, ne_a = n_edges;
        void* args[] = {(void*)&cursor_a, (void*)&off_a, (void*)&part_a,
                        (void*)&RN_a, (void*)&ne_a};
        hipLaunchCooperativeKernel((void*)scan_kernel, dim3(nblk), dim3(256), args, 0, stream);
    }

    place_kernel<<<(n_edges + 255) / 256, 256, 0, stream>>>(ei, et, cursor, sorted_src,
                                                            n_edges, n_nodes);

    int mblk = (n_nodes + BR - 1) / BR;
    fused_kernel<<<mblk, 256, 0, stream>>>(xb, sorted_src, off, WbT, bias, out,
                                           n_nodes, n_rel);
}

// Round 9
// 166.335 us; speedup vs baseline: 1.4665x; 1.4665x over previous
//
#include <hip/hip_runtime.h>
#include <hip/hip_bf16.h>

// SimpleGraphConv (RGCN-mean), fused aggregate-first, register-gather:
//   out[n] = bias + sum_r ( mean_{e: dst=n, type=r} x[src[e]] ) @ W[r]
//
//   1. split counting-sort pipeline (r7 known-good):
//      memset -> pre(hist+wconv+xconv) -> scan1 -> scan2 -> scan3 -> place
//   2. fused kernel (r7 structure + r9 latency fixes):
//      - ALL rels' CSR bounds + first-src hoisted to registers up front
//        (one latency wall instead of 8 serial per-rel chains)
//      - launch_bounds(256,3): reg headroom for load pipelining (r8 showed
//        compiler stays ~84-130; occupancy still grid-limited at 3 blk/CU)
//      - per rel: register gather of MFMA A-fragments, async W stage,
//        2 barriers, 32 MFMA. acc held across rels; out written once.

#define C128 128
#define BR 64

typedef __attribute__((ext_vector_type(8))) short short8;
typedef __attribute__((ext_vector_type(4))) float f32x4;

__device__ __forceinline__ void gload_lds16(void* lds, const void* gsrc) {
    __builtin_amdgcn_global_load_lds(
        (const __attribute__((address_space(1))) unsigned int*)gsrc,
        (__attribute__((address_space(3))) unsigned int*)lds, 16, 0, 0);
}

__device__ __forceinline__ float bf16u_f32(unsigned short u) {
    union { unsigned int i; float f; } c;
    c.i = ((unsigned int)u) << 16;
    return c.f;
}

// ------- merged: hist | wconv | xconv (independent work, block-split) -------

__global__ __launch_bounds__(256) void pre_kernel(const int* __restrict__ ei,
                                                  const int* __restrict__ et,
                                                  unsigned* __restrict__ cursor,
                                                  const float* __restrict__ W,
                                                  __hip_bfloat16* __restrict__ WbT,
                                                  const float* __restrict__ x,
                                                  __hip_bfloat16* __restrict__ xb,
                                                  int n_edges, int n_nodes,
                                                  int hblk, int wblk, int wtot, int xt8) {
    int bid = blockIdx.x;
    if (bid < hblk) {
        int e = bid * 256 + threadIdx.x;
        if (e < n_edges)
            atomicAdd(&cursor[(size_t)et[e] * n_nodes + ei[n_edges + e]], 1u);
    } else if (bid < hblk + wblk) {
        int i = (bid - hblk) * 256 + threadIdx.x;
        if (i < wtot) {
            int r = i >> 14, k = (i >> 7) & 127, n = i & 127;
            WbT[(r << 14) + (n << 7) + ((((k >> 3) ^ (n & 7)) << 3) | (k & 7))] =
                __float2bfloat16(W[i]);
        }
    } else {
        int i = (bid - hblk - wblk) * 256 + threadIdx.x;
        if (i < xt8) {
            const float4* src = reinterpret_cast<const float4*>(x + (size_t)i * 8);
            float4 v0 = src[0], v1 = src[1];
            short8 o;
            o[0] = (short)__bfloat16_as_ushort(__float2bfloat16(v0.x));
            o[1] = (short)__bfloat16_as_ushort(__float2bfloat16(v0.y));
            o[2] = (short)__bfloat16_as_ushort(__float2bfloat16(v0.z));
            o[3] = (short)__bfloat16_as_ushort(__float2bfloat16(v0.w));
            o[4] = (short)__bfloat16_as_ushort(__float2bfloat16(v1.x));
            o[5] = (short)__bfloat16_as_ushort(__float2bfloat16(v1.y));
            o[6] = (short)__bfloat16_as_ushort(__float2bfloat16(v1.z));
            o[7] = (short)__bfloat16_as_ushort(__float2bfloat16(v1.w));
            *reinterpret_cast<short8*>(reinterpret_cast<unsigned short*>(xb) + (size_t)i * 8) = o;
        }
    }
}

// ---------------- scan (3-kernel, split — r7 known-good) ----------------

__global__ __launch_bounds__(256) void scan1_kernel(const unsigned* __restrict__ cnt,
                                                    unsigned* __restrict__ part, int total) {
    __shared__ unsigned s[256];
    int t = threadIdx.x;
    int base = blockIdx.x * 1024 + t * 4;
    unsigned sum = 0;
#pragma unroll
    for (int i = 0; i < 4; ++i) {
        int idx = base + i;
        if (idx < total) sum += cnt[idx];
    }
    s[t] = sum;
    __syncthreads();
    for (int d = 128; d > 0; d >>= 1) {
        if (t < d) s[t] += s[t + d];
        __syncthreads();
    }
    if (t == 0) part[blockIdx.x] = s[0];
}

__global__ __launch_bounds__(512) void scan2_kernel(unsigned* __restrict__ part, int nblk) {
    __shared__ unsigned s[512];
    int t = threadIdx.x;
    unsigned run = 0;
    for (int base = 0; base < nblk; base += 512) {
        int i = base + t;
        unsigned v = (i < nblk) ? part[i] : 0u;
        s[t] = v;
        __syncthreads();
        for (int d = 1; d < 512; d <<= 1) {
            unsigned u = (t >= d) ? s[t - d] : 0u;
            __syncthreads();
            s[t] += u;
            __syncthreads();
        }
        unsigned incl = s[t];
        if (i < nblk) part[i] = run + incl - v;  // exclusive
        unsigned tot = s[511];
        __syncthreads();
        run += tot;
    }
}

__global__ __launch_bounds__(256) void scan3_kernel(unsigned* __restrict__ cursor,
                                                    unsigned* __restrict__ off,
                                                    const unsigned* __restrict__ part,
                                                    int total, int n_edges) {
    __shared__ unsigned s[256];
    int t = threadIdx.x;
    int base = blockIdx.x * 1024 + t * 4;
    unsigned v[4];
    unsigned tsum = 0;
#pragma unroll
    for (int i = 0; i < 4; ++i) {
        int idx = base + i;
        v[i] = (idx < total) ? cursor[idx] : 0u;
        tsum += v[i];
    }
    s[t] = tsum;
    __syncthreads();
    for (int d = 1; d < 256; d <<= 1) {
        unsigned u = (t >= d) ? s[t - d] : 0u;
        __syncthreads();
        s[t] += u;
        __syncthreads();
    }
    unsigned run = s[t] - tsum + part[blockIdx.x];
#pragma unroll
    for (int i = 0; i < 4; ++i) {
        int idx = base + i;
        if (idx < total) {
            off[idx] = run;
            cursor[idx] = run;
            run += v[i];
        }
    }
    if (blockIdx.x == 0 && t == 0) off[total] = (unsigned)n_edges;
}

__global__ __launch_bounds__(256) void place_kernel(const int* __restrict__ ei,
                                                    const int* __restrict__ et,
                                                    unsigned* __restrict__ cursor,
                                                    int* __restrict__ sorted_src,
                                                    int n_edges, int n_nodes) {
    int e = blockIdx.x * 256 + threadIdx.x;
    if (e < n_edges) {
        int src = ei[e];
        int dst = ei[n_edges + e];
        int key = et[e] * n_nodes + dst;
        unsigned pos = atomicAdd(&cursor[key], 1u);
        sorted_src[pos] = src;
    }
}

// ---------------- fused register-gather + MFMA GEMM ----------------

__global__ __launch_bounds__(256, 3) void fused_kernel(
    const __hip_bfloat16* __restrict__ xb, const int* __restrict__ ss,
    const unsigned* __restrict__ off, const __hip_bfloat16* __restrict__ WbT,
    const float* __restrict__ bias, float* __restrict__ out,
    int n_nodes, int n_rel) {
    __shared__ __align__(16) __hip_bfloat16 sW[C128 * C128];  // 32 KB, swizzled
    const int t = threadIdx.x, lane = t & 63, w = t >> 6;
    const int l16 = lane & 15, cg = lane >> 4;
    const int row0 = blockIdx.x * BR;
    const int rl = w * 16 + l16;   // tile row owned (4 cg-lanes per row)
    const int node = row0 + rl;
    const bool live = (node < n_nodes);
    const unsigned short* xbu = reinterpret_cast<const unsigned short*>(xb);

    f32x4 acc[8];
#pragma unroll
    for (int i = 0; i < 8; ++i) acc[i] = (f32x4){0.f, 0.f, 0.f, 0.f};

#define STAGE_W(P)                                                              \
    {                                                                           \
        const char* wp_ = (const char*)(WbT + ((size_t)(P) << 14));             \
        _Pragma("unroll") for (int i_ = 0; i_ < 8; ++i_) {                      \
            int seg_ = i_ * 4 + w;                                              \
            gload_lds16((char*)sW + seg_ * 1024 + lane * 16,                    \
                        wp_ + seg_ * 1024 + lane * 16);                         \
        }                                                                       \
    }

#define MFMA_REL(AF)                                                            \
    _Pragma("unroll") for (int kt_ = 0; kt_ < 4; ++kt_) {                       \
        int chunk_ = kt_ * 4 + cg;                                              \
        _Pragma("unroll") for (int nt_ = 0; nt_ < 8; ++nt_) {                   \
            int wn_ = nt_ * 16 + l16;                                           \
            short8 bf_ = *reinterpret_cast<const short8*>(                      \
                &sW[(wn_ << 7) + ((chunk_ ^ (wn_ & 7)) << 3)]);                 \
            acc[nt_] = __builtin_amdgcn_mfma_f32_16x16x32_bf16(AF[kt_], bf_,    \
                                                               acc[nt_], 0, 0, 0); \
        }                                                                       \
    }

    for (int pb = 0; pb < n_rel; pb += 8) {
        // hoist: all (up to) 8 rels' CSR bounds — 16 independent loads, one wall
        unsigned b8[8], e8[8];
#pragma unroll
        for (int q = 0; q < 8; ++q) {
            b8[q] = 0; e8[q] = 0;
            int p = pb + q;
            if (live && p < n_rel) {
                size_t k0 = (size_t)p * n_nodes + node;
                b8[q] = off[k0];
                e8[q] = off[k0 + 1];
            }
        }
        // hoist: each rel's first src — 8 more independent loads
        int sf8[8];
#pragma unroll
        for (int q = 0; q < 8; ++q)
            sf8[q] = (e8[q] > b8[q]) ? ss[b8[q]] : 0;

#pragma unroll
        for (int q = 0; q < 8; ++q) {
            int p = pb + q;
            if (p >= n_rel) break;                 // uniform across block
            STAGE_W(p);                            // async; overlaps gather

            float a[4][8];
#pragma unroll
            for (int kt = 0; kt < 4; ++kt)
#pragma unroll
                for (int j = 0; j < 8; ++j) a[kt][j] = 0.f;

            int n0 = (int)(e8[q] - b8[q]);
            int s0 = sf8[q];
            int eb = (int)b8[q];
            for (int i = 0; i < n0; ++i) {
                int sv = s0;
                s0 = (i + 1 < n0) ? ss[eb + i + 1] : 0;  // prefetch next src
                const unsigned short* rp = xbu + ((size_t)sv << 7) + cg * 8;
                short8 v0 = *reinterpret_cast<const short8*>(rp);
                short8 v1 = *reinterpret_cast<const short8*>(rp + 32);
                short8 v2 = *reinterpret_cast<const short8*>(rp + 64);
                short8 v3 = *reinterpret_cast<const short8*>(rp + 96);
#pragma unroll
                for (int j = 0; j < 8; ++j) {
                    a[0][j] += bf16u_f32((unsigned short)v0[j]);
                    a[1][j] += bf16u_f32((unsigned short)v1[j]);
                    a[2][j] += bf16u_f32((unsigned short)v2[j]);
                    a[3][j] += bf16u_f32((unsigned short)v3[j]);
                }
            }
            float inv = (n0 > 0) ? 1.0f / (float)n0 : 0.0f;
            short8 af[4];
#pragma unroll
            for (int kt = 0; kt < 4; ++kt) {
                short8 o;
#pragma unroll
                for (int j = 0; j < 8; ++j)
                    o[j] = (short)__bfloat16_as_ushort(__float2bfloat16(a[kt][j] * inv));
                af[kt] = o;
            }
            __syncthreads();   // sW(p) staged (drains vmcnt before barrier)
            MFMA_REL(af);
            __syncthreads();   // sW reads done before next rel restages
        }
    }

    // epilogue: D row = 4*(lane>>4)+i, col = lane&15 (per 16x16 tile)
    const int rbase = row0 + w * 16 + (cg << 2);
#pragma unroll
    for (int nt = 0; nt < 8; ++nt) {
        int col = nt * 16 + l16;
        float b = bias[col];
#pragma unroll
        for (int i = 0; i < 4; ++i) {
            int r = rbase + i;
            if (r < n_nodes)
                out[(size_t)r * C128 + col] = acc[nt][i] + b;
        }
    }
#undef STAGE_W
#undef MFMA_REL
}

// ---------------- host ----------------

static inline char* align16p(char* p) {
    return (char*)(((uintptr_t)p + 15) & ~(uintptr_t)15);
}

extern "C" void kernel_launch(void* const* d_in, const int* in_sizes, int n_in,
                              void* d_out, int out_size, void* d_ws, size_t ws_size,
                              hipStream_t stream) {
    const float* x    = (const float*)d_in[0];
    const int*   ei   = (const int*)d_in[1];   // [2][E]
    const int*   et   = (const int*)d_in[2];   // [E]
    const float* W    = (const float*)d_in[3]; // [R][128][128]
    const float* bias = (const float*)d_in[4]; // [128]
    float* out = (float*)d_out;

    const int n_nodes = in_sizes[0] / C128;
    const int n_edges = in_sizes[2];
    const int n_rel   = in_sizes[3] / (C128 * C128);
    const int RN = n_rel * n_nodes;

    // workspace: off | cursor | part | sorted_src | WbT | xb   (~19 MB)
    char* p = (char*)d_ws;
    unsigned* off = (unsigned*)p;      p += (size_t)(RN + 1) * 4; p = align16p(p);
    unsigned* cursor = (unsigned*)p;   p += (size_t)RN * 4;       p = align16p(p);
    unsigned* part = (unsigned*)p;     p += 4096 * 4;
    int* sorted_src = (int*)p;         p += (size_t)n_edges * 4;  p = align16p(p);
    __hip_bfloat16* WbT = (__hip_bfloat16*)p; p += (size_t)n_rel * C128 * C128 * 2; p = align16p(p);
    __hip_bfloat16* xb = (__hip_bfloat16*)p;

    hipMemsetAsync(cursor, 0, (size_t)RN * 4, stream);

    // hist + wconv + xconv in one launch (right-sized grid, block-range split)
    int wtot = n_rel * C128 * C128;
    int xt8 = n_nodes * (C128 / 8);
    int hblk = (n_edges + 255) / 256;
    int wblk = (wtot + 255) / 256;
    int xblk = (xt8 + 255) / 256;
    pre_kernel<<<hblk + wblk + xblk, 256, 0, stream>>>(ei, et, cursor, W, WbT, x, xb,
                                                       n_edges, n_nodes, hblk, wblk, wtot, xt8);

    int nblk = (RN + 1023) / 1024;
    scan1_kernel<<<nblk, 256, 0, stream>>>(cursor, part, RN);
    scan2_kernel<<<1, 512, 0, stream>>>(part, nblk);
    scan3_kernel<<<nblk, 256, 0, stream>>>(cursor, off, part, RN, n_edges);
    place_kernel<<<(n_edges + 255) / 256, 256, 0, stream>>>(ei, et, cursor, sorted_src,
                                                            n_edges, n_nodes);

    int mblk = (n_nodes + BR - 1) / BR;
    fused_kernel<<<mblk, 256, 0, stream>>>(xb, sorted_src, off, WbT, bias, out,
                                           n_nodes, n_rel);
}

// Round 10
// 149.999 us; speedup vs baseline: 1.6263x; 1.1089x over previous
//
#include <hip/hip_runtime.h>
#include <hip/hip_bf16.h>

// SimpleGraphConv (RGCN-mean), fused aggregate-first, barrier-free register-gather:
//   out[n] = bias + sum_r ( mean_{e: dst=n, type=r} x[src[e]] ) @ W[r]
//
//   1. split counting-sort pipeline:
//      memset -> pre(hist+wconv+xconv) -> scan1 -> scan23(merged) -> place
//   2. fused kernel: 1-wave blocks (16 rows), NO LDS, NO barriers:
//      - W stored fragment-linear [r][kt][nt][lane][16B] -> each B-fragment is
//        one coalesced 1KB wave read from L1/L2 (WbT = 256KB, cache-resident)
//      - lane gathers its MFMA A-fragment (row l16, k-chunks cg+{0,4,8,12})
//        in f32 registers over the row's CSR run (r7 verbatim, known-good)
//      - depth-1 prefetch of next rel's CSR bounds
//      - acc held across rels; out written once. grid = N/16 (no tail).

#define C128 128
#define BR 16

typedef __attribute__((ext_vector_type(8))) short short8;
typedef __attribute__((ext_vector_type(4))) float f32x4;

__device__ __forceinline__ float bf16u_f32(unsigned short u) {
    union { unsigned int i; float f; } c;
    c.i = ((unsigned int)u) << 16;
    return c.f;
}

// ------- merged: hist | wconv | xconv (independent work, block-split) -------
// wconv: fragment-linear layout. W[r][k][n] with k = kt*32+cg*8+j, n = nt*16+l16
//   -> pos = ((((r*4+kt)*8+nt)*4+cg)*16 + l16)*8 + j   (shorts)
// so segment (r,kt,nt) is 1KB contiguous; lane (=cg*16+l16) reads lane*16 bytes.

__global__ __launch_bounds__(256) void pre_kernel(const int* __restrict__ ei,
                                                  const int* __restrict__ et,
                                                  unsigned* __restrict__ cursor,
                                                  const float* __restrict__ W,
                                                  __hip_bfloat16* __restrict__ WbT,
                                                  const float* __restrict__ x,
                                                  __hip_bfloat16* __restrict__ xb,
                                                  int n_edges, int n_nodes,
                                                  int hblk, int wblk, int wtot, int xt8) {
    int bid = blockIdx.x;
    if (bid < hblk) {
        int e = bid * 256 + threadIdx.x;
        if (e < n_edges)
            atomicAdd(&cursor[(size_t)et[e] * n_nodes + ei[n_edges + e]], 1u);
    } else if (bid < hblk + wblk) {
        int i = (bid - hblk) * 256 + threadIdx.x;
        if (i < wtot) {
            int r = i >> 14, k = (i >> 7) & 127, n = i & 127;
            int kt = k >> 5, cg = (k >> 3) & 3, j = k & 7;
            int nt = n >> 4, l16 = n & 15;
            int pos = ((((r * 4 + kt) * 8 + nt) * 4 + cg) * 16 + l16) * 8 + j;
            WbT[pos] = __float2bfloat16(W[i]);
        }
    } else {
        int i = (bid - hblk - wblk) * 256 + threadIdx.x;
        if (i < xt8) {
            const float4* src = reinterpret_cast<const float4*>(x + (size_t)i * 8);
            float4 v0 = src[0], v1 = src[1];
            short8 o;
            o[0] = (short)__bfloat16_as_ushort(__float2bfloat16(v0.x));
            o[1] = (short)__bfloat16_as_ushort(__float2bfloat16(v0.y));
            o[2] = (short)__bfloat16_as_ushort(__float2bfloat16(v0.z));
            o[3] = (short)__bfloat16_as_ushort(__float2bfloat16(v0.w));
            o[4] = (short)__bfloat16_as_ushort(__float2bfloat16(v1.x));
            o[5] = (short)__bfloat16_as_ushort(__float2bfloat16(v1.y));
            o[6] = (short)__bfloat16_as_ushort(__float2bfloat16(v1.z));
            o[7] = (short)__bfloat16_as_ushort(__float2bfloat16(v1.w));
            *reinterpret_cast<short8*>(reinterpret_cast<unsigned short*>(xb) + (size_t)i * 8) = o;
        }
    }
}

// ---------------- scan: scan1 + merged scan23 ----------------

__global__ __launch_bounds__(256) void scan1_kernel(const unsigned* __restrict__ cnt,
                                                    unsigned* __restrict__ part, int total) {
    __shared__ unsigned s[256];
    int t = threadIdx.x;
    int base = blockIdx.x * 1024 + t * 4;
    unsigned sum = 0;
#pragma unroll
    for (int i = 0; i < 4; ++i) {
        int idx = base + i;
        if (idx < total) sum += cnt[idx];
    }
    s[t] = sum;
    __syncthreads();
    for (int d = 128; d > 0; d >>= 1) {
        if (t < d) s[t] += s[t + d];
        __syncthreads();
    }
    if (t == 0) part[blockIdx.x] = s[0];
}

// each block reduces part[0..bid) itself (replaces scan2), then scans its 1024 keys
__global__ __launch_bounds__(256) void scan23_kernel(unsigned* __restrict__ cursor,
                                                     unsigned* __restrict__ off,
                                                     const unsigned* __restrict__ part,
                                                     int total, int n_edges) {
    __shared__ unsigned s[256];
    const int t = threadIdx.x;
    const int bid = blockIdx.x;

    unsigned basesum = 0;
    for (int i0 = 0; i0 < bid; i0 += 256) {
        int i = i0 + t;
        s[t] = (i < bid) ? part[i] : 0u;
        __syncthreads();
        for (int d = 128; d > 0; d >>= 1) {
            if (t < d) s[t] += s[t + d];
            __syncthreads();
        }
        basesum += s[0];
        __syncthreads();
    }

    int base = bid * 1024 + t * 4;
    unsigned v[4];
    unsigned tsum = 0;
#pragma unroll
    for (int i = 0; i < 4; ++i) {
        int idx = base + i;
        v[i] = (idx < total) ? cursor[idx] : 0u;
        tsum += v[i];
    }
    s[t] = tsum;
    __syncthreads();
    for (int d = 1; d < 256; d <<= 1) {
        unsigned u = (t >= d) ? s[t - d] : 0u;
        __syncthreads();
        s[t] += u;
        __syncthreads();
    }
    unsigned run = s[t] - tsum + basesum;
#pragma unroll
    for (int i = 0; i < 4; ++i) {
        int idx = base + i;
        if (idx < total) {
            off[idx] = run;
            cursor[idx] = run;
            run += v[i];
        }
    }
    if (bid == 0 && t == 0) off[total] = (unsigned)n_edges;
}

__global__ __launch_bounds__(256) void place_kernel(const int* __restrict__ ei,
                                                    const int* __restrict__ et,
                                                    unsigned* __restrict__ cursor,
                                                    int* __restrict__ sorted_src,
                                                    int n_edges, int n_nodes) {
    int e = blockIdx.x * 256 + threadIdx.x;
    if (e < n_edges) {
        int src = ei[e];
        int dst = ei[n_edges + e];
        int key = et[e] * n_nodes + dst;
        unsigned pos = atomicAdd(&cursor[key], 1u);
        sorted_src[pos] = src;
    }
}

// ---------------- fused: 1-wave blocks, no LDS, no barriers ----------------

__global__ __launch_bounds__(64, 3) void fused_kernel(
    const __hip_bfloat16* __restrict__ xb, const int* __restrict__ ss,
    const unsigned* __restrict__ off, const __hip_bfloat16* __restrict__ WbT,
    const float* __restrict__ bias, float* __restrict__ out,
    int n_nodes, int n_rel) {
    const int lane = threadIdx.x & 63;
    const int l16 = lane & 15, cg = lane >> 4;
    const int row0 = blockIdx.x * BR;
    const int node = row0 + l16;          // row owned by 4 cg-lanes
    const bool live = (node < n_nodes);
    const unsigned short* xbu = reinterpret_cast<const unsigned short*>(xb);
    const unsigned short* wpu = reinterpret_cast<const unsigned short*>(WbT);

    f32x4 acc[8];
#pragma unroll
    for (int i = 0; i < 8; ++i) acc[i] = (f32x4){0.f, 0.f, 0.f, 0.f};

    unsigned b = 0, e = 0;
    if (live) { b = off[node]; e = off[node + 1]; }   // rel 0 key = node

    for (int p = 0; p < n_rel; ++p) {
        // depth-1 prefetch of next rel's CSR bounds
        unsigned nb = 0, ne = 0;
        if (p + 1 < n_rel && live) {
            size_t k = (size_t)(p + 1) * n_nodes + node;
            nb = off[k];
            ne = off[k + 1];
        }

        // register gather: lane accumulates its 4x8 A-fragment elements
        float a[4][8];
#pragma unroll
        for (int kt = 0; kt < 4; ++kt)
#pragma unroll
            for (int j = 0; j < 8; ++j) a[kt][j] = 0.f;

        int n0 = (int)(e - b);
        int eb = (int)b;
        int s0 = (n0 > 0) ? ss[eb] : 0;
        for (int i = 0; i < n0; ++i) {
            int sv = s0;
            s0 = (i + 1 < n0) ? ss[eb + i + 1] : 0;  // prefetch next src
            const unsigned short* rp = xbu + ((size_t)sv << 7) + cg * 8;
            short8 v0 = *reinterpret_cast<const short8*>(rp);
            short8 v1 = *reinterpret_cast<const short8*>(rp + 32);
            short8 v2 = *reinterpret_cast<const short8*>(rp + 64);
            short8 v3 = *reinterpret_cast<const short8*>(rp + 96);
#pragma unroll
            for (int j = 0; j < 8; ++j) {
                a[0][j] += bf16u_f32((unsigned short)v0[j]);
                a[1][j] += bf16u_f32((unsigned short)v1[j]);
                a[2][j] += bf16u_f32((unsigned short)v2[j]);
                a[3][j] += bf16u_f32((unsigned short)v3[j]);
            }
        }
        float inv = (n0 > 0) ? 1.0f / (float)n0 : 0.0f;
        short8 af[4];
#pragma unroll
        for (int kt = 0; kt < 4; ++kt) {
            short8 o;
#pragma unroll
            for (int j = 0; j < 8; ++j)
                o[j] = (short)__bfloat16_as_ushort(__float2bfloat16(a[kt][j] * inv));
            af[kt] = o;
        }

        // B-fragments straight from global (frag-linear, coalesced 1KB/wave reads)
#pragma unroll
        for (int kt = 0; kt < 4; ++kt) {
            short8 bf[8];
#pragma unroll
            for (int nt = 0; nt < 8; ++nt)
                bf[nt] = *reinterpret_cast<const short8*>(
                    wpu + ((size_t)(((p * 4 + kt) * 8 + nt) * 64 + lane)) * 8);
#pragma unroll
            for (int nt = 0; nt < 8; ++nt)
                acc[nt] = __builtin_amdgcn_mfma_f32_16x16x32_bf16(af[kt], bf[nt],
                                                                  acc[nt], 0, 0, 0);
        }

        b = nb;
        e = ne;
    }

    // epilogue: D row = 4*cg+i, col = nt*16+l16
    const int rbase = row0 + (cg << 2);
#pragma unroll
    for (int nt = 0; nt < 8; ++nt) {
        int col = nt * 16 + l16;
        float bv = bias[col];
#pragma unroll
        for (int i = 0; i < 4; ++i) {
            int r = rbase + i;
            if (r < n_nodes)
                out[(size_t)r * C128 + col] = acc[nt][i] + bv;
        }
    }
}

// ---------------- host ----------------

static inline char* align16p(char* p) {
    return (char*)(((uintptr_t)p + 15) & ~(uintptr_t)15);
}

extern "C" void kernel_launch(void* const* d_in, const int* in_sizes, int n_in,
                              void* d_out, int out_size, void* d_ws, size_t ws_size,
                              hipStream_t stream) {
    const float* x    = (const float*)d_in[0];
    const int*   ei   = (const int*)d_in[1];   // [2][E]
    const int*   et   = (const int*)d_in[2];   // [E]
    const float* W    = (const float*)d_in[3]; // [R][128][128]
    const float* bias = (const float*)d_in[4]; // [128]
    float* out = (float*)d_out;

    const int n_nodes = in_sizes[0] / C128;
    const int n_edges = in_sizes[2];
    const int n_rel   = in_sizes[3] / (C128 * C128);
    const int RN = n_rel * n_nodes;

    // workspace: off | cursor | part | sorted_src | WbT | xb   (~19 MB)
    char* p = (char*)d_ws;
    unsigned* off = (unsigned*)p;      p += (size_t)(RN + 1) * 4; p = align16p(p);
    unsigned* cursor = (unsigned*)p;   p += (size_t)RN * 4;       p = align16p(p);
    unsigned* part = (unsigned*)p;     p += 4096 * 4;
    int* sorted_src = (int*)p;         p += (size_t)n_edges * 4;  p = align16p(p);
    __hip_bfloat16* WbT = (__hip_bfloat16*)p; p += (size_t)n_rel * C128 * C128 * 2; p = align16p(p);
    __hip_bfloat16* xb = (__hip_bfloat16*)p;

    hipMemsetAsync(cursor, 0, (size_t)RN * 4, stream);

    // hist + wconv + xconv in one launch (right-sized grid, block-range split)
    int wtot = n_rel * C128 * C128;
    int xt8 = n_nodes * (C128 / 8);
    int hblk = (n_edges + 255) / 256;
    int wblk = (wtot + 255) / 256;
    int xblk = (xt8 + 255) / 256;
    pre_kernel<<<hblk + wblk + xblk, 256, 0, stream>>>(ei, et, cursor, W, WbT, x, xb,
                                                       n_edges, n_nodes, hblk, wblk, wtot, xt8);

    int nblk = (RN + 1023) / 1024;
    scan1_kernel<<<nblk, 256, 0, stream>>>(cursor, part, RN);
    scan23_kernel<<<nblk, 256, 0, stream>>>(cursor, off, part, RN, n_edges);
    place_kernel<<<(n_edges + 255) / 256, 256, 0, stream>>>(ei, et, cursor, sorted_src,
                                                            n_edges, n_nodes);

    int mblk = (n_nodes + BR - 1) / BR;
    fused_kernel<<<mblk, 64, 0, stream>>>(xb, sorted_src, off, WbT, bias, out,
                                          n_nodes, n_rel);
}